// Round 4
// baseline (18442.172 us; speedup 1.0000x reference)
//
#include <hip/hip_runtime.h>
#include <math.h>

#define K_NN 11
#define B_   1024
#define D_   64
#define A_   4
#define C_   50000
#define NCH  4
#define CPC  12500               // candidates per chunk (C_/NCH)
#define TPC2 196                 // ceil(12500/64) tiles per chunk (last has 20)

// ---------------- K0: s2[a,c] = sum(ts[a,c,:]^2) ----------------
__global__ __launch_bounds__(256) void s2_kernel(const float* __restrict__ ts,
                                                 float* __restrict__ s2g) {
  const int gwid = (blockIdx.x * 256 + threadIdx.x) >> 6;
  const int lane = threadIdx.x & 63;
  const int r0 = gwid * 16;
  if (r0 >= A_ * C_) return;
  const float4* t4 = (const float4*)ts;
  #pragma unroll
  for (int i = 0; i < 4; ++i) {
    const int fi = i * 64 + lane;
    const int r  = r0 + (fi >> 4);
    const int k  = fi & 15;
    float4 v = t4[(size_t)r * 16 + k];
    float acc = v.x*v.x + v.y*v.y + v.z*v.z + v.w*v.w;
    #pragma unroll
    for (int off = 1; off < 16; off <<= 1) acc += __shfl_xor(acc, off, 64);
    if ((lane & 15) == 0) s2g[r] = acc;
  }
}

// ---------------- K1: lane=candidate, 4 rows/wave, per-lane-owned lists ----
// grid 512 = 32 rowgroups x 4 actions x 4 chunks; block 512 thr = 8 waves.
// Each wave: 4 batch rows, full chunk of candidates. Lists: lane&3 owns row.

#define FILTER_ROW(SC, R)                                                    \
  {                                                                          \
    unsigned long long m_ = __ballot((SC) < tau##R);                         \
    while (m_) {                                                             \
      const int l_ = __ffsll(m_) - 1;                                        \
      m_ &= m_ - 1;                                                          \
      const float ssc = __uint_as_float(                                     \
          __builtin_amdgcn_readlane(__float_as_uint(SC), l_));               \
      if (ssc < tau##R) {                                                    \
        const int sidx = c0 + l_;                                            \
        const bool own = (lane & 3) == (R);                                  \
        _Pragma("unroll")                                                    \
        for (int j = K_NN - 1; j >= 1; --j) {                                \
          const bool  sh = best[j-1] > ssc;                                  \
          const float nb = sh ? best[j-1] : ssc;                             \
          const int   ni = sh ? bix[j-1]  : sidx;                            \
          const bool  wr = own && (best[j] > ssc);                           \
          best[j] = wr ? nb : best[j];                                       \
          bix[j]  = wr ? ni : bix[j];                                        \
        }                                                                    \
        const bool w0 = own && (best[0] > ssc);                              \
        bix[0]  = w0 ? sidx : bix[0];                                        \
        best[0] = w0 ? ssc  : best[0];                                       \
        tau##R = __uint_as_float(                                            \
            __builtin_amdgcn_readlane(__float_as_uint(best[K_NN-1]), (R)));  \
      }                                                                      \
    }                                                                        \
  }

#define FMA4(ACC, OV, CV)                                                    \
  ACC = fmaf((CV).x, (OV).x, ACC); ACC = fmaf((CV).y, (OV).y, ACC);          \
  ACC = fmaf((CV).z, (OV).z, ACC); ACC = fmaf((CV).w, (OV).w, ACC);

__global__ __launch_bounds__(512, 4) void qec_kernel(
    const float* __restrict__ obs, const float* __restrict__ ts,
    const float* __restrict__ s2g, float* __restrict__ pscore,
    int* __restrict__ pidx)
{
  __shared__ float sbuf[2][64 * 64];        // 2 x 16 KB, swizzled float4 slots

  const int tid  = threadIdx.x;
  const int lane = tid & 63;
  const int wid  = __builtin_amdgcn_readfirstlane(tid >> 6);
  const int bid  = blockIdx.x;
  // XCD-aware decode: bid%8 (XCD) = a*2 + ch_hi -> same-slice blocks co-XCD
  const int t8   = bid & 7;
  const int a    = t8 >> 1;
  const int rest = bid >> 3;                // 0..63
  const int ch   = ((t8 & 1) << 1) | (rest & 1);
  const int g    = rest >> 1;               // 0..31
  const int b0   = g * 32 + wid * 4;        // this wave's 4 batch rows

  const float* tsa = ts  + (size_t)a * C_ * 64;
  const float* s2a = s2g + (size_t)a * C_;
  const int cbase = ch * CPC;
  const int cend  = cbase + CPC;

  float best[K_NN]; int bix[K_NN];
  #pragma unroll
  for (int j = 0; j < K_NN; ++j) { best[j] = INFINITY; bix[j] = 0; }
  float tau0 = INFINITY, tau1 = INFINITY, tau2 = INFINITY, tau3 = INFINITY;

  // staging: 2 float4 slots/thread; linear global, swizzled LDS write
  const int sA = tid,        rA = sA >> 4, kA = sA & 15;
  const int sB = tid + 512,  rB = sB >> 4, kB = sB & 15;
  const int wsA = rA * 16 + (kA ^ (rA & 15));
  const int wsB = rB * 16 + (kB ^ (rB & 15));

  const float4* g4 = (const float4*)tsa;
  float4 stA, stB;
  {
    int c  = min(cbase + rA, C_ - 1);
    int c2 = min(cbase + rB, C_ - 1);
    stA = g4[(size_t)c  * 16 + kA];
    stB = g4[(size_t)c2 * 16 + kB];
  }

  const float* obase = obs + (size_t)b0 * 64;
  const int lx = lane & 15;

  for (int i = 0; i < TPC2; ++i) {
    const int c0 = cbase + i * 64;
    float4* sp = (float4*)sbuf[i & 1];
    sp[wsA] = stA; sp[wsB] = stB;

    { // issue next tile's global loads early
      int tn = i + 1; if (tn > TPC2 - 1) tn = TPC2 - 1;
      int cb = cbase + tn * 64;
      int c  = min(cb + rA, C_ - 1);
      int c2 = min(cb + rB, C_ - 1);
      stA = g4[(size_t)c  * 16 + kA];
      stB = g4[(size_t)c2 * 16 + kB];
    }
    const int cg = c0 + lane;
    const float s2v = s2a[min(cg, C_ - 1)];

    __syncthreads();

    const float4* rp = (const float4*)sbuf[i & 1];
    const float* op = obase;
    asm volatile("" : "+v"(op));            // defeat cross-tile hoist of obs loads
    float acc0 = 0.f, acc1 = 0.f, acc2 = 0.f, acc3 = 0.f;
    #pragma unroll
    for (int d4 = 0; d4 < 16; ++d4) {
      const float4 cv = rp[lane * 16 + (d4 ^ lx)];
      const float4 o0 = *(const float4*)(op +   0 + d4 * 4);
      const float4 o1 = *(const float4*)(op +  64 + d4 * 4);
      const float4 o2 = *(const float4*)(op + 128 + d4 * 4);
      const float4 o3 = *(const float4*)(op + 192 + d4 * 4);
      FMA4(acc0, o0, cv); FMA4(acc1, o1, cv);
      FMA4(acc2, o2, cv); FMA4(acc3, o3, cv);
    }
    const bool valid = cg < cend;
    float sc0 = valid ? fmaf(-2.f, acc0, s2v) : INFINITY;
    float sc1 = valid ? fmaf(-2.f, acc1, s2v) : INFINITY;
    float sc2 = valid ? fmaf(-2.f, acc2, s2v) : INFINITY;
    float sc3 = valid ? fmaf(-2.f, acc3, s2v) : INFINITY;

    FILTER_ROW(sc0, 0);
    FILTER_ROW(sc1, 1);
    FILTER_ROW(sc2, 2);
    FILTER_ROW(sc3, 3);

    __syncthreads();
  }

  // output: lanes 0..3 hold the canonical list of row b0+lane
  if (lane < 4) {
    const int b = b0 + lane;
    const size_t base = (((size_t)b * A_ + a) * NCH + ch) * K_NN;
    #pragma unroll
    for (int j = 0; j < K_NN; ++j) {
      pscore[base + j] = best[j];
      pidx[base + j]   = bix[j];
    }
  }
}

// ---------------- K2: merge partial top-k, gather qvals, mean ----------------
__global__ __launch_bounds__(256) void merge_kernel(
    const float* __restrict__ pscore, const int* __restrict__ pidx,
    const float* __restrict__ qvals, float* __restrict__ qec)
{
  const int tt = blockIdx.x * 256 + threadIdx.x;  // tt = b*A + a
  if (tt >= B_ * A_) return;
  const int a = tt % A_;

  float best[K_NN]; int bix[K_NN];
  #pragma unroll
  for (int j = 0; j < K_NN; ++j) { best[j] = INFINITY; bix[j] = 0x7fffffff; }

  const float* ps = pscore + (size_t)tt * NCH * K_NN;
  const int*   pi = pidx   + (size_t)tt * NCH * K_NN;

  #pragma unroll
  for (int e = 0; e < NCH * K_NN; ++e) {
    float sc = ps[e]; int ci = pi[e];
    bool lt_last = (sc < best[K_NN-1]) || (sc == best[K_NN-1] && ci < bix[K_NN-1]);
    if (lt_last) {
      #pragma unroll
      for (int j = K_NN-1; j >= 1; --j) {
        bool  s1 = (best[j-1] > sc) || (best[j-1] == sc && bix[j-1] > ci);
        float nb = s1 ? best[j-1] : sc;
        int   ni = s1 ? bix[j-1]  : ci;
        bool  wr = (best[j] > sc) || (best[j] == sc && bix[j] > ci);
        if (wr) { best[j] = nb; bix[j] = ni; }
      }
      bool w0 = (best[0] > sc) || (best[0] == sc && bix[0] > ci);
      if (w0) { best[0] = sc; bix[0] = ci; }
    }
  }

  const float* qa = qvals + (size_t)a * C_;
  float s = 0.f;
  #pragma unroll
  for (int j = 0; j < K_NN; ++j) s += qa[bix[j]];
  qec[tt] = s / (float)K_NN;
}

// ---------------- K3: MLP + combine + argmax ----------------
__global__ __launch_bounds__(256) void mlp_kernel(
    const float* __restrict__ obs, const float* __restrict__ qec,
    const float* __restrict__ W1, const float* __restrict__ b1,
    const float* __restrict__ W2, const float* __restrict__ b2,
    const float* __restrict__ W3, const float* __restrict__ b3,
    float* __restrict__ out)
{
  const int wave = threadIdx.x >> 6;
  const int lane = threadIdx.x & 63;
  const int b = blockIdx.x * 4 + wave;

  float x = obs[(size_t)b * 64 + lane];

  float acc = b1[lane];
  #pragma unroll 8
  for (int d = 0; d < 64; ++d)
    acc = fmaf(__shfl(x, d, 64), W1[d * 64 + lane], acc);
  float h1 = fmaxf(acc, 0.f);

  float acc2 = b2[lane];
  #pragma unroll 8
  for (int d = 0; d < 64; ++d)
    acc2 = fmaf(__shfl(h1, d, 64), W2[d * 64 + lane], acc2);
  float h2 = fmaxf(acc2, 0.f);

  float p0 = h2 * W3[lane * 4 + 0];
  float p1 = h2 * W3[lane * 4 + 1];
  float p2 = h2 * W3[lane * 4 + 2];
  float p3 = h2 * W3[lane * 4 + 3];
  #pragma unroll
  for (int off = 32; off > 0; off >>= 1) {
    p0 += __shfl_xor(p0, off, 64);
    p1 += __shfl_xor(p1, off, 64);
    p2 += __shfl_xor(p2, off, 64);
    p3 += __shfl_xor(p3, off, 64);
  }

  if (lane == 0) {
    float q0 = 0.5f * (qec[b * 4 + 0] + (p0 + b3[0]));
    float q1 = 0.5f * (qec[b * 4 + 1] + (p1 + b3[1]));
    float q2 = 0.5f * (qec[b * 4 + 2] + (p2 + b3[2]));
    float q3 = 0.5f * (qec[b * 4 + 3] + (p3 + b3[3]));
    int am = 0; float m = q0;
    if (q1 > m) { m = q1; am = 1; }
    if (q2 > m) { m = q2; am = 2; }
    if (q3 > m) { m = q3; am = 3; }
    out[b] = (float)am;
    float* qrow = out + B_ + (size_t)b * 4;
    qrow[0] = q0; qrow[1] = q1; qrow[2] = q2; qrow[3] = q3;
  }
}

extern "C" void kernel_launch(void* const* d_in, const int* in_sizes, int n_in,
                              void* d_out, int out_size, void* d_ws, size_t ws_size,
                              hipStream_t stream) {
  const float* obs = (const float*)d_in[0];
  const float* ts  = (const float*)d_in[1];
  const float* qv  = (const float*)d_in[2];
  const float* W1  = (const float*)d_in[3];
  const float* b1  = (const float*)d_in[4];
  const float* W2  = (const float*)d_in[5];
  const float* b2  = (const float*)d_in[6];
  const float* W3  = (const float*)d_in[7];
  const float* b3  = (const float*)d_in[8];
  float* out = (float*)d_out;

  float* s2g    = (float*)d_ws;                                   // A*C
  float* qec    = s2g + (size_t)A_ * C_;                          // B*A
  float* pscore = qec + (size_t)B_ * A_;                          // B*A*NCH*K
  int*   pidx   = (int*)(pscore + (size_t)B_ * A_ * NCH * K_NN);  // same

  s2_kernel<<<dim3((A_ * C_ / 16 + 3) / 4), dim3(256), 0, stream>>>(ts, s2g);
  qec_kernel<<<dim3(512), dim3(512), 0, stream>>>(obs, ts, s2g, pscore, pidx);
  merge_kernel<<<dim3((B_ * A_ + 255) / 256), dim3(256), 0, stream>>>(pscore, pidx, qv, qec);
  mlp_kernel<<<dim3(B_ / 4), dim3(256), 0, stream>>>(obs, qec, W1, b1, W2, b2, W3, b3, out);
}

// Round 5
// 1769.306 us; speedup vs baseline: 10.4234x; 10.4234x over previous
//
#include <hip/hip_runtime.h>
#include <math.h>

#define K_NN 11
#define B_   1024
#define D_   64
#define A_   4
#define C_   50000
#define NCH  4
#define CPC  12500               // candidates per chunk
#define NTC  49                  // tiles per chunk (48 full + 212-tail)
#define LDP  260                 // padded LDS row (floats): mult of 4 (b128-aligned reads)

// ---------------- K0: s2[a,c] = sum(ts[a,c,:]^2) ----------------
__global__ __launch_bounds__(256) void s2_kernel(const float* __restrict__ ts,
                                                 float* __restrict__ s2g) {
  const int gwid = (blockIdx.x * 256 + threadIdx.x) >> 6;
  const int lane = threadIdx.x & 63;
  const int r0 = gwid * 16;
  if (r0 >= A_ * C_) return;
  const float4* t4 = (const float4*)ts;
  #pragma unroll
  for (int i = 0; i < 4; ++i) {
    const int fi = i * 64 + lane;
    const int r  = r0 + (fi >> 4);
    const int k  = fi & 15;
    float4 v = t4[(size_t)r * 16 + k];
    float acc = v.x*v.x + v.y*v.y + v.z*v.z + v.w*v.w;
    #pragma unroll
    for (int off = 1; off < 16; off <<= 1) acc += __shfl_xor(acc, off, 64);
    if ((lane & 15) == 0) s2g[r] = acc;
  }
}

// ---------------- K1: d-major LDS tile, distributed obs, lane=4 cands ------
// grid 512 = 32 rowgroups x 4 actions x 4 chunks; block 256 thr = 4 waves.
// Wave owns 8 batch rows (o[r] = obs[row][lane], lane=dim). Tile: 32d x 256c.

__global__ __launch_bounds__(256) void qec_kernel(
    const float* __restrict__ obs, const float* __restrict__ ts,
    const float* __restrict__ s2g, float* __restrict__ pscore,
    int* __restrict__ pidx)
{
  __shared__ float sb[2][32 * LDP];         // 2 x 33,280 B

  const int tid  = threadIdx.x;
  const int lane = tid & 63;
  const int w    = tid >> 6;
  const int x    = blockIdx.x & 15;         // (a,ch) -> consistent XCD slice
  const int a    = x >> 2;
  const int ch   = x & 3;
  const int rg   = blockIdx.x >> 4;         // 0..31
  const int b0w  = rg * 32 + w * 8;         // this wave's 8 rows

  const float* tsa = ts  + (size_t)a * C_ * 64;
  const float* s2a = s2g + (size_t)a * C_;
  const int cbase = ch * CPC;
  const int cend  = cbase + CPC;

  // distributed obs: o[r] holds obs[b0w+r][lane]  (8 VGPRs, loaded once)
  float o[8];
  #pragma unroll
  for (int r = 0; r < 8; ++r) o[r] = obs[(size_t)(b0w + r) * 64 + lane];

  float best[K_NN]; int bix[K_NN];
  float tau[8]; int tix[8];
  #pragma unroll
  for (int j = 0; j < K_NN; ++j) { best[j] = INFINITY; bix[j] = 0x7fffffff; }
  #pragma unroll
  for (int r = 0; r < 8; ++r) { tau[r] = INFINITY; tix[r] = 0x7fffffff; }

  // staging constants: thread covers dgrp (4 dims) for 4 candidate-pairs
  const int dgrp = tid & 7;                 // 0..7 -> dims dgrp*4..+3 within half
  const int cph  = tid >> 3;                // 0..31

  float acc[4][8];

  auto STAGE = [&](int buf, int ct, int h) {
    const int c0s = min(cbase + ct * 256, C_ - 256);
    const float* src = tsa + (size_t)c0s * 64 + h * 32;
    float* dst = &sb[buf][0];
    #pragma unroll
    for (int i = 0; i < 4; ++i) {
      const int cl = i * 64 + 2 * cph;      // even, 0..254
      const float4 v1 = *(const float4*)(src + (size_t)cl * 64 + dgrp * 4);
      const float4 v2 = *(const float4*)(src + (size_t)(cl + 1) * 64 + dgrp * 4);
      *(float2*)&dst[(dgrp*4+0)*LDP + cl] = make_float2(v1.x, v2.x);
      *(float2*)&dst[(dgrp*4+1)*LDP + cl] = make_float2(v1.y, v2.y);
      *(float2*)&dst[(dgrp*4+2)*LDP + cl] = make_float2(v1.z, v2.z);
      *(float2*)&dst[(dgrp*4+3)*LDP + cl] = make_float2(v1.w, v2.w);
    }
  };

  // prologue
  STAGE(0, 0, 0);
  __syncthreads();

  float4 sq4 = make_float4(0.f, 0.f, 0.f, 0.f);

  for (int s = 0; s < 2 * NTC; ++s) {
    const int ct  = s >> 1;
    const int h   = s & 1;
    const int c0u = cbase + ct * 256;
    const int c0  = min(c0u, C_ - 256);

    if (s + 1 < 2 * NTC) STAGE((s + 1) & 1, (s + 1) >> 1, (s + 1) & 1);

    if (h == 0) {
      #pragma unroll
      for (int ci = 0; ci < 4; ++ci)
        #pragma unroll
        for (int r = 0; r < 8; ++r) acc[ci][r] = 0.f;
      sq4 = *(const float4*)(s2a + c0 + 4 * lane);   // prefetch s2 for this tile
    }

    // compute: 32 d-steps from buffer s&1
    {
      const float* sbp = &sb[s & 1][0];
      const int hb = h * 32;
      #pragma unroll 8
      for (int dl = 0; dl < 32; ++dl) {
        const float4 cv = *(const float4*)&sbp[dl * LDP + 4 * lane];
        const int da = hb + dl;
        #pragma unroll
        for (int r = 0; r < 8; ++r) {
          const float ov = __uint_as_float(
              __builtin_amdgcn_readlane(__float_as_uint(o[r]), da));
          acc[0][r] = fmaf(cv.x, ov, acc[0][r]);
          acc[1][r] = fmaf(cv.y, ov, acc[1][r]);
          acc[2][r] = fmaf(cv.z, ov, acc[2][r]);
          acc[3][r] = fmaf(cv.w, ov, acc[3][r]);
        }
      }
    }

    if (h == 1) {
      // selection: lexicographic (score, idx) shared-tau filter
      const float sqv[4] = {sq4.x, sq4.y, sq4.z, sq4.w};
      #pragma unroll
      for (int ci = 0; ci < 4; ++ci) {
        const int cid = c0 + 4 * lane + ci;
        const bool valid = (cid >= c0u) && (cid < cend);
        #pragma unroll
        for (int r = 0; r < 8; ++r) {
          const float sc = fmaf(-2.f, acc[ci][r], sqv[ci]);
          const bool pass = valid &&
              ((sc < tau[r]) || (sc == tau[r] && cid < tix[r]));
          unsigned long long m = __ballot(pass);
          while (m) {
            const int l_ = __ffsll(m) - 1;
            m &= m - 1;
            const float ssc = __uint_as_float(
                __builtin_amdgcn_readlane(__float_as_uint(sc), l_));
            const int sid = c0 + 4 * l_ + ci;
            if ((ssc < tau[r]) || (ssc == tau[r] && sid < tix[r])) {
              const bool own = (lane == r);
              #pragma unroll
              for (int j = K_NN - 1; j >= 1; --j) {
                const bool  s1 = (best[j-1] > ssc) ||
                                 (best[j-1] == ssc && bix[j-1] > sid);
                const float nb = s1 ? best[j-1] : ssc;
                const int   ni = s1 ? bix[j-1]  : sid;
                const bool  wr = own && ((best[j] > ssc) ||
                                         (best[j] == ssc && bix[j] > sid));
                best[j] = wr ? nb : best[j];
                bix[j]  = wr ? ni : bix[j];
              }
              const bool w0 = own && ((best[0] > ssc) ||
                                      (best[0] == ssc && bix[0] > sid));
              bix[0]  = w0 ? sid : bix[0];
              best[0] = w0 ? ssc : best[0];
              tau[r] = __uint_as_float(
                  __builtin_amdgcn_readlane(__float_as_uint(best[K_NN-1]), r));
              tix[r] = __builtin_amdgcn_readlane(bix[K_NN-1], r);
            }
          }
        }
      }
    }

    __syncthreads();
  }

  // output: lane r (0..7) owns row b0w+r
  if (lane < 8) {
    const int b = b0w + lane;
    const size_t base = (((size_t)b * A_ + a) * NCH + ch) * K_NN;
    #pragma unroll
    for (int j = 0; j < K_NN; ++j) {
      pscore[base + j] = best[j];
      pidx[base + j]   = bix[j];
    }
  }
}

// ---------------- K2: merge partial top-k, gather qvals, mean ----------------
__global__ __launch_bounds__(256) void merge_kernel(
    const float* __restrict__ pscore, const int* __restrict__ pidx,
    const float* __restrict__ qvals, float* __restrict__ qec)
{
  const int tt = blockIdx.x * 256 + threadIdx.x;  // tt = b*A + a
  if (tt >= B_ * A_) return;
  const int a = tt % A_;

  float best[K_NN]; int bix[K_NN];
  #pragma unroll
  for (int j = 0; j < K_NN; ++j) { best[j] = INFINITY; bix[j] = 0x7fffffff; }

  const float* ps = pscore + (size_t)tt * NCH * K_NN;
  const int*   pi = pidx   + (size_t)tt * NCH * K_NN;

  #pragma unroll
  for (int e = 0; e < NCH * K_NN; ++e) {
    float sc = ps[e]; int ci = pi[e];
    bool lt_last = (sc < best[K_NN-1]) || (sc == best[K_NN-1] && ci < bix[K_NN-1]);
    if (lt_last) {
      #pragma unroll
      for (int j = K_NN-1; j >= 1; --j) {
        bool  s1 = (best[j-1] > sc) || (best[j-1] == sc && bix[j-1] > ci);
        float nb = s1 ? best[j-1] : sc;
        int   ni = s1 ? bix[j-1]  : ci;
        bool  wr = (best[j] > sc) || (best[j] == sc && bix[j] > ci);
        if (wr) { best[j] = nb; bix[j] = ni; }
      }
      bool w0 = (best[0] > sc) || (best[0] == sc && bix[0] > ci);
      if (w0) { best[0] = sc; bix[0] = ci; }
    }
  }

  const float* qa = qvals + (size_t)a * C_;
  float s = 0.f;
  #pragma unroll
  for (int j = 0; j < K_NN; ++j) s += qa[bix[j]];
  qec[tt] = s / (float)K_NN;
}

// ---------------- K3: MLP + combine + argmax ----------------
__global__ __launch_bounds__(256) void mlp_kernel(
    const float* __restrict__ obs, const float* __restrict__ qec,
    const float* __restrict__ W1, const float* __restrict__ b1,
    const float* __restrict__ W2, const float* __restrict__ b2,
    const float* __restrict__ W3, const float* __restrict__ b3,
    float* __restrict__ out)
{
  const int wave = threadIdx.x >> 6;
  const int lane = threadIdx.x & 63;
  const int b = blockIdx.x * 4 + wave;

  float x = obs[(size_t)b * 64 + lane];

  float acc = b1[lane];
  #pragma unroll 8
  for (int d = 0; d < 64; ++d)
    acc = fmaf(__shfl(x, d, 64), W1[d * 64 + lane], acc);
  float h1 = fmaxf(acc, 0.f);

  float acc2 = b2[lane];
  #pragma unroll 8
  for (int d = 0; d < 64; ++d)
    acc2 = fmaf(__shfl(h1, d, 64), W2[d * 64 + lane], acc2);
  float h2 = fmaxf(acc2, 0.f);

  float p0 = h2 * W3[lane * 4 + 0];
  float p1 = h2 * W3[lane * 4 + 1];
  float p2 = h2 * W3[lane * 4 + 2];
  float p3 = h2 * W3[lane * 4 + 3];
  #pragma unroll
  for (int off = 32; off > 0; off >>= 1) {
    p0 += __shfl_xor(p0, off, 64);
    p1 += __shfl_xor(p1, off, 64);
    p2 += __shfl_xor(p2, off, 64);
    p3 += __shfl_xor(p3, off, 64);
  }

  if (lane == 0) {
    float q0 = 0.5f * (qec[b * 4 + 0] + (p0 + b3[0]));
    float q1 = 0.5f * (qec[b * 4 + 1] + (p1 + b3[1]));
    float q2 = 0.5f * (qec[b * 4 + 2] + (p2 + b3[2]));
    float q3 = 0.5f * (qec[b * 4 + 3] + (p3 + b3[3]));
    int am = 0; float m = q0;
    if (q1 > m) { m = q1; am = 1; }
    if (q2 > m) { m = q2; am = 2; }
    if (q3 > m) { m = q3; am = 3; }
    out[b] = (float)am;
    float* qrow = out + B_ + (size_t)b * 4;
    qrow[0] = q0; qrow[1] = q1; qrow[2] = q2; qrow[3] = q3;
  }
}

extern "C" void kernel_launch(void* const* d_in, const int* in_sizes, int n_in,
                              void* d_out, int out_size, void* d_ws, size_t ws_size,
                              hipStream_t stream) {
  const float* obs = (const float*)d_in[0];
  const float* ts  = (const float*)d_in[1];
  const float* qv  = (const float*)d_in[2];
  const float* W1  = (const float*)d_in[3];
  const float* b1  = (const float*)d_in[4];
  const float* W2  = (const float*)d_in[5];
  const float* b2  = (const float*)d_in[6];
  const float* W3  = (const float*)d_in[7];
  const float* b3  = (const float*)d_in[8];
  float* out = (float*)d_out;

  float* s2g    = (float*)d_ws;                                   // A*C
  float* qec    = s2g + (size_t)A_ * C_;                          // B*A
  float* pscore = qec + (size_t)B_ * A_;                          // B*A*NCH*K
  int*   pidx   = (int*)(pscore + (size_t)B_ * A_ * NCH * K_NN);  // same

  s2_kernel<<<dim3((A_ * C_ / 16 + 3) / 4), dim3(256), 0, stream>>>(ts, s2g);
  qec_kernel<<<dim3(512), dim3(256), 0, stream>>>(obs, ts, s2g, pscore, pidx);
  merge_kernel<<<dim3((B_ * A_ + 255) / 256), dim3(256), 0, stream>>>(pscore, pidx, qv, qec);
  mlp_kernel<<<dim3(B_ / 4), dim3(256), 0, stream>>>(obs, qec, W1, b1, W2, b2, W3, b3, out);
}